// Round 8
// baseline (396.790 us; speedup 1.0000x reference)
//
#include <hip/hip_runtime.h>

// BoostedNeuralLDPCDecoder — MI355X HIP implementation (round 12)
//
// r11 (all-LDS, 64 blocks/CUs) was LATENCY-bound: 8 scattered global tot
// loads per CN unit (~200 cy L2) with only 4 waves/SIMD; VALUBusy(any-SIMD)
// 74% on active CUs but true issue ~20%. HBM at 3% — memory is idle.
//
// r12: compact check-state + everything-in-LDS.
//   state[(M+1)][Z] u32: {sign(8b) | ismin(8b) | qm1(4b) | qm2(4b)} per
//     (cn,zc) — reconstructs all 8 messages of a check (they take only two
//     magnitudes). Row M=46 is a zero dummy for padded gather slots.
//   acc[N][Z] int16: sum of 2x-messages; tot == xa + 0.5f*acc recomputed
//     (same one-rounding fp add as before -> bit-exact).
//   CN decode: 1 ds_read_b32 (own state) + 8 ds_read_i16 (acc) + 8 CACHED
//     xa loads, xa prefetched 2-deep (ping-pong regs, static indexing).
//   CN store: one ds_write_b32 (vs 8 byte writes). VN: deg x ds_read_b32 +
//     ~7 VALU extraction; message values identical to the old stored bytes
//     (qm = fminf(15, rintf(w*m*2)) in the ORIGINAL expression order;
//     rintf odd + symmetric clamp => sign factorization exact; m2=BIG and
//     all-tie cases produce the same +-15).
//   LDS: 72,192 (state) + 52,224 (acc) dynamic + 17,680 (tiles) + 6,528
//     (sev u32) + 272 (sdeg) static = 148.9 KB <= 160 KiB. 1 block/CU.
// Output path (17x64 tile transpose) verbatim r11. absmax must stay 0.0.

#define ITERS 5
#define Nn 68
#define Mm 46
#define Zz 384
#define Ee 368
#define Bb 64
#define Kk 8          // edges per CN (E/M)
#define PADD 24       // padded max VN degree (r4-proven sufficient)
#define BIGF 1e9f

#define BLKT 1024
#define CNU (Mm*Zz)                      // 17,664 check-lane units per batch
#define OUT_ITER ((size_t)Bb*Zz*Nn)
#define STATE_DW ((Mm+1)*Zz)             // 18,048 u32 incl zero row 46
#define DYN_LDS (STATE_DW*4 + Nn*Zz*2)   // 72,192 + 52,224 = 124,416 B

// sev u32 pack: [14:0]=cn*Zz (state dword base), [23:15]=shift, [26:24]=k
#define DUMMY_SEV ((unsigned)(Mm*Zz))    // dummy row, sh=0, k=0 -> msg 0

// ---- message reconstruction: value identical to the r4-stored byte ----
__device__ __forceinline__ int msg_from_state(unsigned st, int k) {
    int mag = ((st >> (8 + k)) & 1u) ? (int)((st >> 20) & 15u)
                                     : (int)((st >> 16) & 15u);
    return ((st >> k) & 1u) ? -mag : mag;
}

// ---- CN unit: issue all loads (xa cached, acc/state LDS), no waits ----
template<bool FIRST>
__device__ __forceinline__ void cn_issue(
    const float* __restrict__ xab, const unsigned* __restrict__ state,
    const short* __restrict__ acc,
    const int* __restrict__ edge_vn, const int* __restrict__ edge_shift,
    int u, float xv[Kk], int av[Kk], unsigned* sv)
{
    const int cn = __builtin_amdgcn_readfirstlane(u) / Zz;  // wave-uniform
    const int zc = u - cn * Zz;          // per-lane lifted row
    #pragma unroll
    for (int k = 0; k < Kk; k++) {
        int e  = cn + k * Mm;            // edge of this check (edge_cn = e%M)
        int sh = edge_shift[e];          // wave-uniform -> scalar load
        int n  = edge_vn[e];             // wave-uniform
        int z  = zc - sh;
        z += (z >> 31) & Zz;             // mod Z
        int zi = n * Zz + z;             // same index for xa and acc
        xv[k] = xab[zi];                 // cached read-only load
        if (!FIRST) av[k] = (int)acc[zi];            // ds_read_i16
    }
    if (!FIRST) *sv = state[u];                      // own prev state
}

// ---- CN unit: consume — verbatim r4 arithmetic via reconstruction ----
template<bool FIRST>
__device__ __forceinline__ void cn_consume(
    unsigned* __restrict__ state, int u, float w,
    const float xv[Kk], const int av[Kk], unsigned sv)
{
    float v[Kk];
    float m1 = BIGF;
    unsigned sflip = 0u;
    #pragma unroll
    for (int k = 0; k < Kk; k++) {
        float t;
        if (FIRST) {
            t = xv[k];                   // tot == xa, c2v == 0 at it 0
        } else {
            t = xv[k] + 0.5f * (float)av[k];         // tot (one rounding)
            t -= 0.5f * (float)msg_from_state(sv, k); // extrinsic (one rounding)
        }
        float x = fminf(20.0f, fmaxf(-20.0f, t));    // allowed_llr_range
        v[k] = x;
        if (x < 0.0f) sflip ^= 1u;
        m1 = fminf(m1, fabsf(x));
    }
    // min2 over entries whose |v| != min1 (reference tie semantics)
    float m2 = BIGF;
    #pragma unroll
    for (int k = 0; k < Kk; k++) {
        float mag = fabsf(v[k]);
        if (mag != m1) m2 = fminf(m2, mag);
    }
    // qms5 magnitudes — SAME expression order as r4's rintf(w*ext*2):
    float q1f = fminf(15.0f, fmaxf(-15.0f, rintf(w * m1 * 2.0f)));
    float q2f = fminf(15.0f, fmaxf(-15.0f, rintf(w * m2 * 2.0f)));
    unsigned st = ((unsigned)(int)q1f << 16) | ((unsigned)(int)q2f << 20);
    #pragma unroll
    for (int k = 0; k < Kk; k++) {
        unsigned im = (fabsf(v[k]) == m1) ? 1u : 0u;
        unsigned ng = sflip ^ ((v[k] < 0.0f) ? 1u : 0u);
        st |= (im << (8 + k)) | (ng << k);
    }
    state[u] = st;                       // one ds_write_b32
}

// ---- CN phase: 2-deep ping-pong pipeline (static reg indexing) ----
template<bool FIRST>
__device__ __forceinline__ void cn_pass(
    const float* __restrict__ xab, unsigned* __restrict__ state,
    const short* __restrict__ acc,
    const int* __restrict__ edge_vn, const int* __restrict__ edge_shift,
    float w, int tid)
{
    const int nu = (tid < CNU - 17 * BLKT) ? 18 : 17;   // wave-uniform
    float xA[Kk], xB[Kk];
    int   aA[Kk], aB[Kk];
    unsigned sA = 0u, sB = 0u;
    int u = tid, i = 0;
    cn_issue<FIRST>(xab, state, acc, edge_vn, edge_shift, u, xA, aA, &sA);
    for (;;) {
        if (i + 1 < nu)
            cn_issue<FIRST>(xab, state, acc, edge_vn, edge_shift,
                            u + BLKT, xB, aB, &sB);
        cn_consume<FIRST>(state, u, w, xA, aA, sA);
        if (i + 1 >= nu) break;
        u += BLKT; ++i;
        if (i + 1 < nu)
            cn_issue<FIRST>(xab, state, acc, edge_vn, edge_shift,
                            u + BLKT, xA, aA, &sA);
        cn_consume<FIRST>(state, u, w, xB, aB, sB);
        if (i + 1 >= nu) break;
        u += BLKT; ++i;
    }
}

// ---- VN gather: one ds_read_b32 + extraction (scalarized descriptor) ----
__device__ __forceinline__ int vn_gather(
    const unsigned* __restrict__ state, unsigned svd, int z)
{
    unsigned sv = __builtin_amdgcn_readfirstlane(svd);  // wave-uniform
    int base = (int)(sv & 0x7FFFu);
    int sh   = (int)((sv >> 15) & 0x1FFu);
    int k    = (int)(sv >> 24);
    int zg = z + sh;
    if (zg >= Zz) zg -= Zz;
    return msg_from_state(state[base + zg], k);
}

// ---- VN phase: 4 teams x 256 threads; team = n-chunk, 6 z-tiles each ----
__device__ __forceinline__ void vn_pass(
    const float* __restrict__ xab, const unsigned* __restrict__ state,
    short* __restrict__ acc, float* __restrict__ out_g,
    const unsigned* __restrict__ sev, const int* __restrict__ sdeg,
    int write_acc, float (*tile)[65], int team, int ttid)
{
    const int wave = ttid >> 6;          // 0..3 within team
    const int lane = ttid & 63;
    const int n0 = team * 17;            // n-chunk per team (4 x 17 = 68)

    for (int zq = 0; zq < 6; ++zq) {
        const int z0 = zq * 64;
        const int z  = z0 + lane;

        for (int i = wave; i < 17; i += 4) {
            int n = __builtin_amdgcn_readfirstlane(n0 + i);
            int d = __builtin_amdgcn_readfirstlane(sdeg[n]);
            const unsigned* vo = sev + n * PADD;
            int accs = 0;                // sum of 2x-messages: exact int
            #pragma unroll
            for (int j = 0; j < 8; j++) accs += vn_gather(state, vo[j], z);
            if (d > 8) {
                #pragma unroll
                for (int j = 8; j < 16; j++) accs += vn_gather(state, vo[j], z);
            }
            if (d > 16) {
                #pragma unroll
                for (int j = 16; j < PADD; j++) accs += vn_gather(state, vo[j], z);
            }
            float s = xab[n * Zz + z] + 0.5f * (float)accs;  // one rounding
            if (write_acc) acc[n * Zz + z] = (short)accs;    // ds_write_b16
            tile[i][lane] = s;
        }
        __syncthreads();                 // block-wide; all teams at same zq

        // out[it][b][z][n]: 64 z-rows x 17 contiguous floats (68 B segments);
        // the 4 teams' segments at each z are adjacent -> L2 write-merge
        float* dst = out_g + (size_t)z0 * Nn + n0;
        for (int idx = ttid; idx < 17 * 64; idx += 256) {
            int zz = idx / 17;
            int nn = idx - zz * 17;
            dst[(size_t)zz * Nn + nn] = tile[nn][zz];
        }
        __syncthreads();                 // tile reused by next zq
    }
}

__global__ __launch_bounds__(BLKT, 1) void fused_kernel(
    const float* __restrict__ xa, const float* __restrict__ cn_weight,
    const int* __restrict__ edge_vn, const int* __restrict__ edge_shift,
    float* __restrict__ out)
{
    extern __shared__ unsigned char dyn[];
    unsigned* state = (unsigned*)dyn;                    // [47][384] u32
    short*    acc   = (short*)(dyn + STATE_DW * 4);      // [68][384] i16
    __shared__ float tile[4][17][65];                    // per-team tiles
    __shared__ unsigned sev[Nn * PADD];                  // gather descriptors
    __shared__ int sdeg[Nn];

    const int g   = blockIdx.x;                          // batch b
    const int tid = threadIdx.x;
    const int team = tid >> 8, ttid = tid & 255;

    // ---- per-block tables (order-independent int sums -> bit-exact) ----
    for (int i = tid; i < Nn; i += BLKT) sdeg[i] = 0;
    for (int i = tid; i < Nn * PADD; i += BLKT) sev[i] = DUMMY_SEV;
    __syncthreads();
    if (tid < Ee) {
        int n  = edge_vn[tid];
        int cn = tid % Mm;
        int k  = tid / Mm;
        int sh = edge_shift[tid];
        int slot = atomicAdd(&sdeg[n], 1);
        if (slot < PADD)
            sev[n * PADD + slot] = (unsigned)(cn * Zz)
                                 | ((unsigned)sh << 15) | ((unsigned)k << 24);
    }
    if (tid < Zz) state[Mm * Zz + tid] = 0u;   // zero dummy state row
    __syncthreads();

    const float* xab = xa + (size_t)g * Nn * Zz;         // [n][z] slice

    for (int it = 0; it < ITERS; ++it) {
        const float w = cn_weight[it];
        if (it == 0) cn_pass<true >(xab, state, acc, edge_vn, edge_shift, w, tid);
        else         cn_pass<false>(xab, state, acc, edge_vn, edge_shift, w, tid);
        __syncthreads();                 // state complete for VN
        vn_pass(xab, state, acc,
                out + (size_t)it * OUT_ITER + (size_t)g * Zz * Nn,
                sev, sdeg, (it != ITERS - 1) ? 1 : 0,
                tile[team], team, ttid);
        __syncthreads();                 // acc settled before next CN
    }
}

extern "C" void kernel_launch(void* const* d_in, const int* in_sizes, int n_in,
                              void* d_out, int out_size, void* d_ws, size_t ws_size,
                              hipStream_t stream) {
    const float* xa        = (const float*)d_in[0];  // [B][N][Z]
    const float* cn_weight = (const float*)d_in[1];  // [ITERS]
    const int*   edge_vn   = (const int*)d_in[2];    // [E]
    // d_in[3] = edge_cn: structurally e % M, not needed
    const int*   edge_shift= (const int*)d_in[4];    // [E]
    float* out = (float*)d_out;                      // [ITERS][B][Z][N]

    // allow >64 KB dynamic LDS (host-side, immediate, capture-safe); once
    static int inited = 0;
    if (!inited) {
        (void)hipFuncSetAttribute((const void*)fused_kernel,
                                  hipFuncAttributeMaxDynamicSharedMemorySize,
                                  DYN_LDS);
        inited = 1;
    }

    fused_kernel<<<dim3(Bb), dim3(BLKT), DYN_LDS, stream>>>(
        xa, cn_weight, edge_vn, edge_shift, out);
}